// Round 4
// baseline (376.657 us; speedup 1.0000x reference)
//
#include <hip/hip_runtime.h>
#include <stdint.h>

typedef unsigned short u16;
typedef __bf16 bf16x8 __attribute__((ext_vector_type(8)));
typedef float  f32x4  __attribute__((ext_vector_type(4)));

// ---- problem constants ----
#define SDIM 2048
#define BDIM 8
#define DIN  1024
#define DOUT 4096
#define EDIM 8
#define RDIM 16
#define KAUG 1152            // DIN + E*R
#define MDIM (SDIM*BDIM)     // 16384
#define SCH  32
#define NT   (KAUG/32)       // 36 K-tiles of 32 for the main GEMM

__device__ __forceinline__ u16 f2bf(float f) {
    __bf16 h = (__bf16)f;
    return __builtin_bit_cast(u16, h);
}

__device__ __forceinline__ void gload16(const u16* g, u16* lds) {
    __builtin_amdgcn_global_load_lds(
        (const __attribute__((address_space(1))) void*)g,
        (__attribute__((address_space(3))) void*)lds, 16, 0, 0);
}

#define VMCNT(n)  asm volatile("s_waitcnt vmcnt(" #n ")" ::: "memory")

// ---------------------------------------------------------------------------
// k1: per-(b, s-chunk) partial sums of x over s + bf16 convert into Xb
// ---------------------------------------------------------------------------
__global__ __launch_bounds__(256) void k1_reduce_convert(
    const float* __restrict__ x, u16* __restrict__ Xb, float* __restrict__ P)
{
    const int b  = blockIdx.x;
    const int sc = blockIdx.y;
    const int i  = threadIdx.x * 4;
    float a0 = 0.f, a1 = 0.f, a2 = 0.f, a3 = 0.f;
    const int s0 = sc * (SDIM / SCH);
    for (int s = s0; s < s0 + (SDIM / SCH); ++s) {
        const float4 v = *reinterpret_cast<const float4*>(
            &x[((size_t)s * BDIM + b) * DIN + i]);
        a0 += v.x; a1 += v.y; a2 += v.z; a3 += v.w;
        ushort4 u{f2bf(v.x), f2bf(v.y), f2bf(v.z), f2bf(v.w)};
        *reinterpret_cast<ushort4*>(&Xb[((size_t)s * BDIM + b) * KAUG + i]) = u;
    }
    float4 p{a0, a1, a2, a3};
    *reinterpret_cast<float4*>(&P[((size_t)sc * BDIM + b) * DIN + i]) = p;
}

// ---------------------------------------------------------------------------
// k2: gate weights
// ---------------------------------------------------------------------------
__global__ __launch_bounds__(256) void k2_gates(
    const float* __restrict__ P, const float* __restrict__ gw,
    const float* __restrict__ gb, float* __restrict__ g)
{
    const int e = blockIdx.x, b = blockIdx.y, t = threadIdx.x;
    float dot = 0.f;
    for (int i = t; i < DIN; i += 256) {
        float xs = 0.f;
        #pragma unroll
        for (int c = 0; c < SCH; ++c) xs += P[((size_t)c * BDIM + b) * DIN + i];
        dot += xs * gw[(size_t)e * DIN + i];
    }
    __shared__ float red[256];
    red[t] = dot;
    __syncthreads();
    #pragma unroll
    for (int off = 128; off > 0; off >>= 1) {
        if (t < off) red[t] += red[t + off];
        __syncthreads();
    }
    if (t == 0) g[b * EDIM + e] = red[0] * (1.0f / SDIM) + gb[e];
}

// ---------------------------------------------------------------------------
// kw: build Waug
// ---------------------------------------------------------------------------
__global__ __launch_bounds__(256) void kw_build_waug(
    const float* __restrict__ W, const float* __restrict__ lb, u16* __restrict__ Waug)
{
    const int o = blockIdx.x, t = threadIdx.x;
    for (int i = t; i < DIN; i += 256)
        Waug[(size_t)o * KAUG + i] = f2bf(W[(size_t)o * DIN + i]);
    if (t < EDIM * RDIM) {
        const int e = t >> 4, r = t & 15;
        Waug[(size_t)o * KAUG + DIN + t] =
            f2bf(lb[((size_t)e * DOUT + o) * RDIM + r]);
    }
}

__global__ __launch_bounds__(256) void kl_convert(
    const float* __restrict__ la, u16* __restrict__ LAb)
{
    const int idx = blockIdx.x * 256 + threadIdx.x;
    if (idx < EDIM * RDIM * DIN) LAb[idx] = f2bf(la[idx]);
}

__global__ __launch_bounds__(256) void k4_scale_u(
    const float* __restrict__ T, const float* __restrict__ g, u16* __restrict__ Xb)
{
    const int idx = blockIdx.x * 256 + threadIdx.x;
    const int m = idx >> 7, er = idx & 127;
    const int b = m & (BDIM - 1), e = er >> 4;
    const float u = g[b * EDIM + e] * T[idx];
    Xb[(size_t)m * KAUG + DIN + er] = f2bf(u);
}

// ---------------------------------------------------------------------------
// gemm_bt: R0 128x128 kernel — used only for the small LoRA GEMM (N=128)
// ---------------------------------------------------------------------------
template <int ADD_BIAS>
__global__ __launch_bounds__(256) void gemm_bt(
    const u16* __restrict__ A, int lda,
    const u16* __restrict__ B, int ldb,
    float* __restrict__ C, int ldc,
    const float* __restrict__ bias, int ktiles)
{
    __shared__ __align__(16) u16 As[8][128][8];
    __shared__ __align__(16) u16 Bs[8][128][8];

    const int tid  = threadIdx.x;
    const int lane = tid & 63;
    const int l15  = lane & 15;
    const int l4   = lane >> 4;
    const int wid  = tid >> 6;
    const int wr   = wid >> 1;
    const int wc   = wid & 1;
    const int m0 = blockIdx.y * 128;
    const int n0 = blockIdx.x * 128;
    const int mr  = tid & 127;
    const int chi = tid >> 7;

    f32x4 acc[4][4] = {};

    for (int kt = 0; kt < ktiles; ++kt) {
        #pragma unroll
        for (int q = 0; q < 4; ++q) {
            const int c    = q * 2 + chi;
            const int kofs = kt * 64 + c * 8;
            u16* ldsbase   = (u16*)As + (size_t)(q * 256 + (tid & 192)) * 8;
            gload16(A + (size_t)(m0 + mr) * lda + kofs, ldsbase);
            u16* ldsbaseB  = (u16*)Bs + (size_t)(q * 256 + (tid & 192)) * 8;
            gload16(B + (size_t)(n0 + mr) * ldb + kofs, ldsbaseB);
        }
        __syncthreads();
        #pragma unroll
        for (int ks = 0; ks < 2; ++ks) {
            const int c = ks * 4 + l4;
            bf16x8 av[4], bv[4];
            #pragma unroll
            for (int mi = 0; mi < 4; ++mi)
                av[mi] = *reinterpret_cast<const bf16x8*>(
                    &As[c][wr * 64 + mi * 16 + l15][0]);
            #pragma unroll
            for (int ni = 0; ni < 4; ++ni)
                bv[ni] = *reinterpret_cast<const bf16x8*>(
                    &Bs[c][wc * 64 + ni * 16 + l15][0]);
            #pragma unroll
            for (int mi = 0; mi < 4; ++mi)
                #pragma unroll
                for (int ni = 0; ni < 4; ++ni)
                    acc[mi][ni] = __builtin_amdgcn_mfma_f32_16x16x32_bf16(
                        av[mi], bv[ni], acc[mi][ni], 0, 0, 0);
        }
        __syncthreads();
    }

    #pragma unroll
    for (int mi = 0; mi < 4; ++mi) {
        const int r0 = m0 + wr * 64 + mi * 16 + l4 * 4;
        #pragma unroll
        for (int ni = 0; ni < 4; ++ni) {
            const int col = n0 + wc * 64 + ni * 16 + l15;
            const float badd = ADD_BIAS ? bias[col] : 0.0f;
            float* cp = C + (size_t)r0 * ldc + col;
            #pragma unroll
            for (int r = 0; r < 4; ++r)
                cp[(size_t)r * ldc] = acc[mi][ni][r] + badd;
        }
    }
}

// ---------------------------------------------------------------------------
// gemm_main: out = Xaug[16384x1152] * Waug[4096x1152]^T + bias, fp32 out.
// BM=BN=256, BK=32, 512 thr (8 waves 2Mx4N, per-wave 128x64), ring-4 LDS.
// R3: fine-grained sub-phase interleave (m201-style) — per iter:
//   VMCNT(4) -> BAR -> SA(j+3) -> read avH(j) -> SB(j+3)
//   -> MFMA-lo(j) [avL/bv read last iter] -> read avL/bv(j+1) -> MFMA-hi(j)
// vmcnt ledger (steady): before top, outstanding = tile j+2 (4 insts);
//   VMCNT(4) confirms ALL tiles <= j+1 for this wave; the barrier then makes
//   every wave's j+1 stage visible => mid-iter reads of tile j+1 are safe.
// Tail: j>=NT-2 -> VMCNT(0) (last 2 iters only).
// WAR ring: SA/SB(j+3) overwrite buf (j-1)&3 after the iter-j barrier; that
// buffer's last reads completed before each wave's preceding MFMA issue
// (compiler lgkm waits) which precede barrier arrival. Safe.
// LDS k-slab [buf][slab4][row256][8]: 0 bank conflicts (PMC-verified R0-R2),
// linear lane-order dest for global_load_lds.
// ---------------------------------------------------------------------------
__global__ __launch_bounds__(512) void gemm_main(
    const u16* __restrict__ A, const u16* __restrict__ B,
    float* __restrict__ C, const float* __restrict__ bias)
{
    __shared__ __align__(16) u16 As[4][4][256][8];   // 64 KiB
    __shared__ __align__(16) u16 Bs[4][4][256][8];   // 64 KiB

    const int tid  = threadIdx.x;
    const int lane = tid & 63;
    const int l15  = lane & 15;
    const int l4   = lane >> 4;
    const int wid  = tid >> 6;      // 0..7
    const int wm   = wid >> 2;      // 0..1  (128-row half)
    const int wn   = wid & 3;       // 0..3  (64-col quarter)

    // T1: XCD-aware swizzle (nwg = 16*64 = 1024, % 8 == 0)
    const int f   = blockIdx.x + blockIdx.y * gridDim.x;
    const int cpx = (gridDim.x * gridDim.y) >> 3;
    const int s_  = (f & 7) * cpx + (f >> 3);
    const int m0  = (s_ / gridDim.x) * 256;
    const int n0  = (s_ % gridDim.x) * 256;

    f32x4  acc[8][4] = {};
    bf16x8 avL[2][4], avH[4], bv[2][4];

    auto SA = [&](int kt, int buf) {
        u16* baseA = &As[buf][0][0][0];
        #pragma unroll
        for (int i = 0; i < 2; ++i) {
            const int cix = i * 512 + tid;           // slab=cix>>8, row=cix&255
            gload16(A + (size_t)(m0 + (cix & 255)) * KAUG + kt * 32 + (cix >> 8) * 8,
                    baseA + cix * 8);
        }
    };
    auto SB = [&](int kt, int buf) {
        u16* baseB = &Bs[buf][0][0][0];
        #pragma unroll
        for (int i = 0; i < 2; ++i) {
            const int cix = i * 512 + tid;
            gload16(B + (size_t)(n0 + (cix & 255)) * KAUG + kt * 32 + (cix >> 8) * 8,
                    baseB + cix * 8);
        }
    };
    auto RdAvL = [&](int buf, bf16x8* dst) {
        #pragma unroll
        for (int mf = 0; mf < 4; ++mf)
            dst[mf] = *reinterpret_cast<const bf16x8*>(
                &As[buf][l4][wm * 128 + mf * 16 + l15][0]);
    };
    auto RdAvH = [&](int buf) {
        #pragma unroll
        for (int mf = 0; mf < 4; ++mf)
            avH[mf] = *reinterpret_cast<const bf16x8*>(
                &As[buf][l4][wm * 128 + (4 + mf) * 16 + l15][0]);
    };
    auto RdBv = [&](int buf, bf16x8* dst) {
        #pragma unroll
        for (int nf = 0; nf < 4; ++nf)
            dst[nf] = *reinterpret_cast<const bf16x8*>(
                &Bs[buf][l4][wn * 64 + nf * 16 + l15][0]);
    };
    auto MfmaLo = [&](bf16x8* a, bf16x8* b) {
        __builtin_amdgcn_s_setprio(1);
        #pragma unroll
        for (int i = 0; i < 4; ++i)
            #pragma unroll
            for (int nf = 0; nf < 4; ++nf)
                acc[i][nf] = __builtin_amdgcn_mfma_f32_16x16x32_bf16(
                    a[i], b[nf], acc[i][nf], 0, 0, 0);
        __builtin_amdgcn_s_setprio(0);
    };
    auto MfmaHi = [&](bf16x8* b) {
        __builtin_amdgcn_s_setprio(1);
        #pragma unroll
        for (int i = 0; i < 4; ++i)
            #pragma unroll
            for (int nf = 0; nf < 4; ++nf)
                acc[4 + i][nf] = __builtin_amdgcn_mfma_f32_16x16x32_bf16(
                    avH[i], b[nf], acc[4 + i][nf], 0, 0, 0);
        __builtin_amdgcn_s_setprio(0);
    };

    // prologue: stage tiles 0,1,2 (12 insts); confirm tile 0; read its lo-frags
    SA(0, 0); SB(0, 0); SA(1, 1); SB(1, 1); SA(2, 2); SB(2, 2);
    VMCNT(8);
    __builtin_amdgcn_s_barrier();
    RdAvL(0, avL[0]); RdBv(0, bv[0]);

    #define BODY(J, ALPHA, TOPW, DOSTG, DOMID)                              \
    do {                                                                    \
        asm volatile("s_waitcnt vmcnt(" TOPW ")" ::: "memory");             \
        __builtin_amdgcn_s_barrier();                                       \
        if (DOSTG) SA((J) + 3, ((J) + 3) & 3);                              \
        RdAvH((J) & 3);                                                     \
        if (DOSTG) SB((J) + 3, ((J) + 3) & 3);                              \
        MfmaLo(avL[ALPHA], bv[ALPHA]);                                      \
        if (DOMID) { RdAvL(((J) + 1) & 3, avL[(ALPHA) ^ 1]);                \
                     RdBv(((J) + 1) & 3, bv[(ALPHA) ^ 1]); }                \
        MfmaHi(bv[ALPHA]);                                                  \
    } while (0)

    for (int j = 0; j < NT - 4; j += 2) {      // j = 0..30 (bodies 0..31)
        BODY(j,     0, "4", true, true);
        BODY(j + 1, 1, "4", true, true);
    }
    BODY(32, 0, "4", true,  true);
    BODY(33, 1, "4", false, true);
    BODY(34, 0, "0", false, true);
    BODY(35, 1, "0", false, false);
    #undef BODY

    // ---- epilogue: row=(l>>4)*4+reg, col=l&15 per fragment ----
    #pragma unroll
    for (int mf = 0; mf < 8; ++mf) {
        const int row0 = m0 + wm * 128 + mf * 16 + l4 * 4;
        #pragma unroll
        for (int nf = 0; nf < 4; ++nf) {
            const int col = n0 + wn * 64 + nf * 16 + l15;
            const float badd = bias[col];
            float* cp = C + (size_t)row0 * DOUT + col;
            #pragma unroll
            for (int q = 0; q < 4; ++q)
                cp[(size_t)q * DOUT] = acc[mf][nf][q] + badd;
        }
    }
}

// ---------------------------------------------------------------------------
extern "C" void kernel_launch(void* const* d_in, const int* in_sizes, int n_in,
                              void* d_out, int out_size, void* d_ws, size_t ws_size,
                              hipStream_t stream)
{
    const float* x    = (const float*)d_in[0];
    const float* gw   = (const float*)d_in[1];
    const float* gb   = (const float*)d_in[2];
    const float* W    = (const float*)d_in[3];
    const float* bias = (const float*)d_in[4];
    const float* la   = (const float*)d_in[5];
    const float* lb   = (const float*)d_in[6];
    float* out = (float*)d_out;

    char* ws = (char*)d_ws;
    u16*   Xb   = (u16*)(ws);                       // 37,748,736 B
    u16*   Waug = (u16*)(ws + 37748736);            //  9,437,184 B
    float* T    = (float*)(ws + 47185920);          //  8,388,608 B
    float* P    = (float*)(ws + 55574528);          //  1,048,576 B
    u16*   LAb  = (u16*)(ws + 56623104);            //    262,144 B
    float* G    = (float*)(ws + 56885248);          //        256 B

    k1_reduce_convert<<<dim3(BDIM, SCH), 256, 0, stream>>>(x, Xb, P);
    kw_build_waug<<<DOUT, 256, 0, stream>>>(W, lb, Waug);
    kl_convert<<<(EDIM * RDIM * DIN + 255) / 256, 256, 0, stream>>>(la, LAb);
    k2_gates<<<dim3(EDIM, BDIM), 256, 0, stream>>>(P, gw, gb, G);
    gemm_bt<0><<<dim3(1, MDIM / 128), 256, 0, stream>>>(
        Xb, KAUG, LAb, DIN, T, EDIM * RDIM, nullptr, DIN / 64);
    k4_scale_u<<<(MDIM * EDIM * RDIM) / 256, 256, 0, stream>>>(T, G, Xb);
    gemm_main<<<dim3(DOUT / 256, MDIM / 256), 512, 0, stream>>>(
        Xb, Waug, out, bias);
}

// Round 5
// 282.142 us; speedup vs baseline: 1.3350x; 1.3350x over previous
//
#include <hip/hip_runtime.h>
#include <stdint.h>

typedef unsigned short u16;
typedef __bf16 bf16x8 __attribute__((ext_vector_type(8)));
typedef float  f32x4  __attribute__((ext_vector_type(4)));

// ---- problem constants ----
#define SDIM 2048
#define BDIM 8
#define DIN  1024
#define DOUT 4096
#define EDIM 8
#define RDIM 16
#define KAUG 1152            // DIN + E*R
#define MDIM (SDIM*BDIM)     // 16384
#define SCH  32
#define NT2  18              // K-tiles of 64 for the main GEMM

__device__ __forceinline__ u16 f2bf(float f) {
    __bf16 h = (__bf16)f;
    return __builtin_bit_cast(u16, h);
}

__device__ __forceinline__ void gload16(const u16* g, u16* lds) {
    __builtin_amdgcn_global_load_lds(
        (const __attribute__((address_space(1))) void*)g,
        (__attribute__((address_space(3))) void*)lds, 16, 0, 0);
}

#define VMCNT(n)  asm volatile("s_waitcnt vmcnt(" #n ")" ::: "memory")

// ---------------------------------------------------------------------------
// k1: per-(b, s-chunk) partial sums of x over s + bf16 convert into Xb
// ---------------------------------------------------------------------------
__global__ __launch_bounds__(256) void k1_reduce_convert(
    const float* __restrict__ x, u16* __restrict__ Xb, float* __restrict__ P)
{
    const int b  = blockIdx.x;
    const int sc = blockIdx.y;
    const int i  = threadIdx.x * 4;
    float a0 = 0.f, a1 = 0.f, a2 = 0.f, a3 = 0.f;
    const int s0 = sc * (SDIM / SCH);
    for (int s = s0; s < s0 + (SDIM / SCH); ++s) {
        const float4 v = *reinterpret_cast<const float4*>(
            &x[((size_t)s * BDIM + b) * DIN + i]);
        a0 += v.x; a1 += v.y; a2 += v.z; a3 += v.w;
        ushort4 u{f2bf(v.x), f2bf(v.y), f2bf(v.z), f2bf(v.w)};
        *reinterpret_cast<ushort4*>(&Xb[((size_t)s * BDIM + b) * KAUG + i]) = u;
    }
    float4 p{a0, a1, a2, a3};
    *reinterpret_cast<float4*>(&P[((size_t)sc * BDIM + b) * DIN + i]) = p;
}

// ---------------------------------------------------------------------------
// k2: gate weights
// ---------------------------------------------------------------------------
__global__ __launch_bounds__(256) void k2_gates(
    const float* __restrict__ P, const float* __restrict__ gw,
    const float* __restrict__ gb, float* __restrict__ g)
{
    const int e = blockIdx.x, b = blockIdx.y, t = threadIdx.x;
    float dot = 0.f;
    for (int i = t; i < DIN; i += 256) {
        float xs = 0.f;
        #pragma unroll
        for (int c = 0; c < SCH; ++c) xs += P[((size_t)c * BDIM + b) * DIN + i];
        dot += xs * gw[(size_t)e * DIN + i];
    }
    __shared__ float red[256];
    red[t] = dot;
    __syncthreads();
    #pragma unroll
    for (int off = 128; off > 0; off >>= 1) {
        if (t < off) red[t] += red[t + off];
        __syncthreads();
    }
    if (t == 0) g[b * EDIM + e] = red[0] * (1.0f / SDIM) + gb[e];
}

// ---------------------------------------------------------------------------
// kw: build Waug
// ---------------------------------------------------------------------------
__global__ __launch_bounds__(256) void kw_build_waug(
    const float* __restrict__ W, const float* __restrict__ lb, u16* __restrict__ Waug)
{
    const int o = blockIdx.x, t = threadIdx.x;
    for (int i = t; i < DIN; i += 256)
        Waug[(size_t)o * KAUG + i] = f2bf(W[(size_t)o * DIN + i]);
    if (t < EDIM * RDIM) {
        const int e = t >> 4, r = t & 15;
        Waug[(size_t)o * KAUG + DIN + t] =
            f2bf(lb[((size_t)e * DOUT + o) * RDIM + r]);
    }
}

__global__ __launch_bounds__(256) void kl_convert(
    const float* __restrict__ la, u16* __restrict__ LAb)
{
    const int idx = blockIdx.x * 256 + threadIdx.x;
    if (idx < EDIM * RDIM * DIN) LAb[idx] = f2bf(la[idx]);
}

__global__ __launch_bounds__(256) void k4_scale_u(
    const float* __restrict__ T, const float* __restrict__ g, u16* __restrict__ Xb)
{
    const int idx = blockIdx.x * 256 + threadIdx.x;
    const int m = idx >> 7, er = idx & 127;
    const int b = m & (BDIM - 1), e = er >> 4;
    const float u = g[b * EDIM + e] * T[idx];
    Xb[(size_t)m * KAUG + DIN + er] = f2bf(u);
}

// ---------------------------------------------------------------------------
// gemm_bt: R0 128x128 kernel — used only for the small LoRA GEMM (N=128)
// ---------------------------------------------------------------------------
template <int ADD_BIAS>
__global__ __launch_bounds__(256) void gemm_bt(
    const u16* __restrict__ A, int lda,
    const u16* __restrict__ B, int ldb,
    float* __restrict__ C, int ldc,
    const float* __restrict__ bias, int ktiles)
{
    __shared__ __align__(16) u16 As[8][128][8];
    __shared__ __align__(16) u16 Bs[8][128][8];

    const int tid  = threadIdx.x;
    const int lane = tid & 63;
    const int l15  = lane & 15;
    const int l4   = lane >> 4;
    const int wid  = tid >> 6;
    const int wr   = wid >> 1;
    const int wc   = wid & 1;
    const int m0 = blockIdx.y * 128;
    const int n0 = blockIdx.x * 128;
    const int mr  = tid & 127;
    const int chi = tid >> 7;

    f32x4 acc[4][4] = {};

    for (int kt = 0; kt < ktiles; ++kt) {
        #pragma unroll
        for (int q = 0; q < 4; ++q) {
            const int c    = q * 2 + chi;
            const int kofs = kt * 64 + c * 8;
            u16* ldsbase   = (u16*)As + (size_t)(q * 256 + (tid & 192)) * 8;
            gload16(A + (size_t)(m0 + mr) * lda + kofs, ldsbase);
            u16* ldsbaseB  = (u16*)Bs + (size_t)(q * 256 + (tid & 192)) * 8;
            gload16(B + (size_t)(n0 + mr) * ldb + kofs, ldsbaseB);
        }
        __syncthreads();
        #pragma unroll
        for (int ks = 0; ks < 2; ++ks) {
            const int c = ks * 4 + l4;
            bf16x8 av[4], bv[4];
            #pragma unroll
            for (int mi = 0; mi < 4; ++mi)
                av[mi] = *reinterpret_cast<const bf16x8*>(
                    &As[c][wr * 64 + mi * 16 + l15][0]);
            #pragma unroll
            for (int ni = 0; ni < 4; ++ni)
                bv[ni] = *reinterpret_cast<const bf16x8*>(
                    &Bs[c][wc * 64 + ni * 16 + l15][0]);
            #pragma unroll
            for (int mi = 0; mi < 4; ++mi)
                #pragma unroll
                for (int ni = 0; ni < 4; ++ni)
                    acc[mi][ni] = __builtin_amdgcn_mfma_f32_16x16x32_bf16(
                        av[mi], bv[ni], acc[mi][ni], 0, 0, 0);
        }
        __syncthreads();
    }

    #pragma unroll
    for (int mi = 0; mi < 4; ++mi) {
        const int r0 = m0 + wr * 64 + mi * 16 + l4 * 4;
        #pragma unroll
        for (int ni = 0; ni < 4; ++ni) {
            const int col = n0 + wc * 64 + ni * 16 + l15;
            const float badd = ADD_BIAS ? bias[col] : 0.0f;
            float* cp = C + (size_t)r0 * ldc + col;
            #pragma unroll
            for (int r = 0; r < 4; ++r)
                cp[(size_t)r * ldc] = acc[mi][ni][r] + badd;
        }
    }
}

// ---------------------------------------------------------------------------
// gemm_main R4: m201-style phase schedule, adapted.
// BM=BN=256, BK=64, NT2=18, 512 thr (8 waves 2Mx4N, per-wave 128x64),
// ring-2 LDS dbuf (128 KiB), k-slab layout (0 bank conflicts, PMC R0-R3).
// Stage unit = half-tile (16 KB = 2 gload16/thread). Units u=0..71,
// u%4: {A-h0, A-h1, B-h0, B-h1}, buf=(u>>2)&1. Lead L=5: unit u issued at
// global phase u-5 (one unit per phase, 4 phases per K-tile).
// Phase p of tile j: {ds_read A-quarter p (4 b128; p==0 also B-panel 8 b128)
//   -> stage unit 4j+5+p -> setprio(1) 16 MFMA setprio(0)
//   -> [p==3: VMCNT(2), tails 0] -> s_barrier}
// vmcnt ledger at phase(j,3): issued through unit 4j+8 -> VMCNT(2) confirms
// tile j+1 (units <= 4j+7). j==NT2-2: VMCNT(0) (last stage was unit 71).
// WAR: unit u's buffer slot overwritten by u+8, staged at phase u+3; u's last
// reads complete (data-dep before MFMA issue) before barrier(u+2-ish) --
// >=1 full barrier separation. Queue never drains until last 2 tiles.
// ---------------------------------------------------------------------------
__global__ __launch_bounds__(512) void gemm_main(
    const u16* __restrict__ A, const u16* __restrict__ B,
    float* __restrict__ C, const float* __restrict__ bias)
{
    __shared__ __align__(16) u16 As[2][2][8][128][8];   // [buf][half][slab][row][8] 64 KiB
    __shared__ __align__(16) u16 Bs[2][2][8][128][8];   // 64 KiB

    const int tid  = threadIdx.x;
    const int lane = tid & 63;
    const int l15  = lane & 15;
    const int l4   = lane >> 4;
    const int wid  = tid >> 6;      // 0..7
    const int wm   = wid >> 2;      // 0..1  (128-row half)
    const int wn   = wid & 3;       // 0..3  (64-col quarter)

    // T1: XCD-aware swizzle (nwg = 16*64 = 1024, % 8 == 0)
    const int f   = blockIdx.x + blockIdx.y * gridDim.x;
    const int cpx = (gridDim.x * gridDim.y) >> 3;
    const int s_  = (f & 7) * cpx + (f >> 3);
    const int m0  = (s_ / gridDim.x) * 256;
    const int n0  = (s_ % gridDim.x) * 256;

    f32x4  acc[8][4] = {};
    bf16x8 aq[2][2], bv[4][2];

    auto stage = [&](int s) {
        const int kt = s >> 2, part = s & 3, buf = kt & 1, hf = part & 1;
        #pragma unroll
        for (int i = 0; i < 2; ++i) {
            const int cix  = i * 512 + tid;
            const int row  = cix & 127, slab = cix >> 7;
            if (part < 2)
                gload16(A + (size_t)(m0 + hf * 128 + row) * KAUG + kt * 64 + slab * 8,
                        &As[buf][hf][slab][row][0]);
            else
                gload16(B + (size_t)(n0 + hf * 128 + row) * KAUG + kt * 64 + slab * 8,
                        &Bs[buf][hf][slab][row][0]);
        }
    };

    // prologue: units 0..4 (tile 0 fully + A-h0 of tile 1) = 10 gloads
    stage(0); stage(1); stage(2); stage(3); stage(4);
    VMCNT(2);                       // confirm units 0..3 (tile 0); unit 4 in flight
    __builtin_amdgcn_s_barrier();

    #define PHASE(P)                                                            \
    do {                                                                        \
        if ((P) == 0) {                                                         \
            _Pragma("unroll") for (int nf = 0; nf < 4; ++nf)                    \
                _Pragma("unroll") for (int kk = 0; kk < 2; ++kk)                \
                    bv[nf][kk] = *reinterpret_cast<const bf16x8*>(              \
                        &Bs[buf][wn >> 1][kk * 4 + l4]                          \
                           [(wn & 1) * 64 + nf * 16 + l15][0]);                 \
        }                                                                       \
        _Pragma("unroll") for (int fr = 0; fr < 2; ++fr)                        \
            _Pragma("unroll") for (int kk = 0; kk < 2; ++kk)                    \
                aq[fr][kk] = *reinterpret_cast<const bf16x8*>(                  \
                    &As[buf][wm][kk * 4 + l4][(P) * 32 + fr * 16 + l15][0]);    \
        { const int su = 4 * j + 5 + (P); if (su < 4 * NT2) stage(su); }        \
        __builtin_amdgcn_s_setprio(1);                                          \
        _Pragma("unroll") for (int kk = 0; kk < 2; ++kk)                        \
            _Pragma("unroll") for (int fr = 0; fr < 2; ++fr)                    \
                _Pragma("unroll") for (int nf = 0; nf < 4; ++nf)                \
                    acc[(P) * 2 + fr][nf] =                                     \
                        __builtin_amdgcn_mfma_f32_16x16x32_bf16(                \
                            aq[fr][kk], bv[nf][kk], acc[(P) * 2 + fr][nf],      \
                            0, 0, 0);                                           \
        __builtin_amdgcn_s_setprio(0);                                          \
        if ((P) == 3) { if (j < NT2 - 2) VMCNT(2); else VMCNT(0); }             \
        __builtin_amdgcn_s_barrier();                                           \
    } while (0)

    for (int j = 0; j < NT2; ++j) {
        const int buf = j & 1;
        PHASE(0);
        PHASE(1);
        PHASE(2);
        PHASE(3);
    }
    #undef PHASE

    // ---- epilogue: row = wm*128 + a*16 + l4*4, col per fragment ----
    #pragma unroll
    for (int a = 0; a < 8; ++a) {
        const int row0 = m0 + wm * 128 + a * 16 + l4 * 4;
        #pragma unroll
        for (int nf = 0; nf < 4; ++nf) {
            const int col = n0 + wn * 64 + nf * 16 + l15;
            const float badd = bias[col];
            float* cp = C + (size_t)row0 * DOUT + col;
            #pragma unroll
            for (int q = 0; q < 4; ++q)
                cp[(size_t)q * DOUT] = acc[a][nf][q] + badd;
        }
    }
}

// ---------------------------------------------------------------------------
extern "C" void kernel_launch(void* const* d_in, const int* in_sizes, int n_in,
                              void* d_out, int out_size, void* d_ws, size_t ws_size,
                              hipStream_t stream)
{
    const float* x    = (const float*)d_in[0];
    const float* gw   = (const float*)d_in[1];
    const float* gb   = (const float*)d_in[2];
    const float* W    = (const float*)d_in[3];
    const float* bias = (const float*)d_in[4];
    const float* la   = (const float*)d_in[5];
    const float* lb   = (const float*)d_in[6];
    float* out = (float*)d_out;

    char* ws = (char*)d_ws;
    u16*   Xb   = (u16*)(ws);                       // 37,748,736 B
    u16*   Waug = (u16*)(ws + 37748736);            //  9,437,184 B
    float* T    = (float*)(ws + 47185920);          //  8,388,608 B
    float* P    = (float*)(ws + 55574528);          //  1,048,576 B
    u16*   LAb  = (u16*)(ws + 56623104);            //    262,144 B
    float* G    = (float*)(ws + 56885248);          //        256 B

    k1_reduce_convert<<<dim3(BDIM, SCH), 256, 0, stream>>>(x, Xb, P);
    kw_build_waug<<<DOUT, 256, 0, stream>>>(W, lb, Waug);
    kl_convert<<<(EDIM * RDIM * DIN + 255) / 256, 256, 0, stream>>>(la, LAb);
    k2_gates<<<dim3(EDIM, BDIM), 256, 0, stream>>>(P, gw, gb, G);
    gemm_bt<0><<<dim3(1, MDIM / 128), 256, 0, stream>>>(
        Xb, KAUG, LAb, DIN, T, EDIM * RDIM, nullptr, DIN / 64);
    k4_scale_u<<<(MDIM * EDIM * RDIM) / 256, 256, 0, stream>>>(T, G, Xb);
    gemm_main<<<dim3(DOUT / 256, MDIM / 256), 512, 0, stream>>>(
        Xb, Waug, out, bias);
}